// Round 1
// baseline (519.348 us; speedup 1.0000x reference)
//
#include <hip/hip_runtime.h>
#include <stdint.h>

#define N_NODES 100000
#define DIM     128
#define RANK    8
#define N_REL   16
#define N_EDGE  250000

typedef __attribute__((ext_vector_type(8))) short  short8v;
typedef __attribute__((ext_vector_type(4))) float  float4v;

__device__ inline unsigned short f2bf(float f) {
    union { float f; unsigned u; } v; v.f = f;
    unsigned r = v.u + 0x7fffu + ((v.u >> 16) & 1u);   // round-nearest-even
    return (unsigned short)(r >> 16);
}
__device__ inline float bf2f(unsigned short h) {
    union { unsigned u; float f; } v; v.u = ((unsigned)h) << 16;
    return v.f;
}

// ---------------------------------------------------------------------------
// Weight / embedding fp32 -> bf16 conversion (run once per launch).
// Layout in out (shorts): W[16384] W1[32768] W2[65536] W3[32768] A[16384] B[16384]
// ---------------------------------------------------------------------------
__global__ __launch_bounds__(256) void wcvt_kernel(
    const float* __restrict__ W,  const float* __restrict__ W1,
    const float* __restrict__ W2, const float* __restrict__ W3,
    const float* __restrict__ Ae, const float* __restrict__ Be,
    unsigned short* __restrict__ out)
{
    int i = blockIdx.x * blockDim.x + threadIdx.x;
    const float* src; int off;
    if      (i <  16384) { src = W;  off = 0; }
    else if (i <  49152) { src = W1; off = 16384; }
    else if (i < 114688) { src = W2; off = 49152; }
    else if (i < 147456) { src = W3; off = 114688; }
    else if (i < 163840) { src = Ae; off = 147456; }
    else if (i < 180224) { src = Be; off = 163840; }
    else return;
    out[i] = f2bf(src[i - off]);
}

// ---------------------------------------------------------------------------
// Edge kernel: one wave (64 lanes) per edge; lane owns channels {2l, 2l+1}.
//   Bj[k] = sum_d B[rt][d][k] * x[src][d]      (wave butterfly reduce, k=0..7)
//   adapter[d] = sum_k A[rt][d][k] * Bj[k]
//   msg = y[src] + adapter ; atomicAdd into aggr[dst]
// ---------------------------------------------------------------------------
__global__ __launch_bounds__(256) void edge_kernel(
    const float*          __restrict__ x,
    const int*            __restrict__ eidx,
    const int*            __restrict__ etype,
    const unsigned short* __restrict__ yb,
    const unsigned short* __restrict__ Ab,
    const unsigned short* __restrict__ Bb,
    float*                __restrict__ aggr)
{
    const int wave = threadIdx.x >> 6;
    const int lane = threadIdx.x & 63;
    const int e = blockIdx.x * 4 + wave;
    if (e >= N_EDGE) return;

    const int src = eidx[e];
    const int dst = eidx[N_EDGE + e];
    const int rt  = etype[e];

    const float2 xv = *reinterpret_cast<const float2*>(&x[(size_t)src * DIM + 2 * lane]);

    const unsigned short* Brow = Bb + rt * (DIM * RANK) + 16 * lane;
    short8v b0 = *reinterpret_cast<const short8v*>(Brow);      // d0, k=0..7
    short8v b1 = *reinterpret_cast<const short8v*>(Brow + 8);  // d1, k=0..7

    float p[8];
    #pragma unroll
    for (int k = 0; k < 8; ++k)
        p[k] = bf2f((unsigned short)b0[k]) * xv.x + bf2f((unsigned short)b1[k]) * xv.y;

    #pragma unroll
    for (int off = 1; off < 64; off <<= 1) {
        #pragma unroll
        for (int k = 0; k < 8; ++k) p[k] += __shfl_xor(p[k], off);
    }

    const unsigned short* Arow = Ab + rt * (DIM * RANK) + 16 * lane;
    short8v a0 = *reinterpret_cast<const short8v*>(Arow);
    short8v a1 = *reinterpret_cast<const short8v*>(Arow + 8);
    float ad0 = 0.f, ad1 = 0.f;
    #pragma unroll
    for (int k = 0; k < 8; ++k) {
        ad0 += bf2f((unsigned short)a0[k]) * p[k];
        ad1 += bf2f((unsigned short)a1[k]) * p[k];
    }

    const unsigned short* yrow = yb + (size_t)src * DIM + 2 * lane;
    const float m0 = bf2f(yrow[0]) + ad0;
    const float m1 = bf2f(yrow[1]) + ad1;

    float* arow = aggr + (size_t)dst * DIM + 2 * lane;
    unsafeAtomicAdd(arow,     m0);
    unsafeAtomicAdd(arow + 1, m1);
}

// ---------------------------------------------------------------------------
// Strip GEMM: C[M x NOUT] = act(A[M x K] @ Wb[NOUT x K]^T + bias)
// One wave computes NSTRIP=2 strips of 16 rows, all NOUT cols.
// A-frags in registers (reused across n-tiles); B-frags streamed from L2.
// AMODE: 0 = A fp32,  1 = A = (1+eps)*x + aggr (fp32),  2 = A bf16
// OMODE: 0 = bf16 store,  1 = bf16 relu(v+bias),  2 = fp32 v+bias
// ---------------------------------------------------------------------------
template<int K, int NOUT, int AMODE, int OMODE>
__global__ __launch_bounds__(256) void strip_gemm(
    const void*           __restrict__ Aptr,
    const float*          __restrict__ aggr,
    const float*          __restrict__ epsp,
    const unsigned short* __restrict__ Wb,
    const float*          __restrict__ bias,
    void*                 __restrict__ Out)
{
    constexpr int NSTRIP = 2;
    constexpr int KT = K / 32;
    constexpr int NT = NOUT / 16;
    constexpr int NSTRIPS_TOT = N_NODES / 16;   // 6250

    const int wave = threadIdx.x >> 6;
    const int lane = threadIdx.x & 63;
    const int job  = blockIdx.x * 4 + wave;
    const int strip0 = job * NSTRIP;
    if (strip0 >= NSTRIPS_TOT) return;

    const int row16 = lane & 15;   // A-row within strip; also output col within n-tile
    const int kgrp  = lane >> 4;   // 0..3

    short8v afrag[NSTRIP][KT];
    #pragma unroll
    for (int s = 0; s < NSTRIP; ++s) {
        const int m = (strip0 + s) * 16 + row16;
        #pragma unroll
        for (int kt = 0; kt < KT; ++kt) {
            const int k0 = kt * 32 + kgrp * 8;
            if constexpr (AMODE == 2) {
                afrag[s][kt] = *reinterpret_cast<const short8v*>(
                    (const unsigned short*)Aptr + (size_t)m * K + k0);
            } else {
                const float* ap = (const float*)Aptr + (size_t)m * K + k0;
                float4v v0 = *reinterpret_cast<const float4v*>(ap);
                float4v v1 = *reinterpret_cast<const float4v*>(ap + 4);
                if constexpr (AMODE == 1) {
                    const float s1 = 1.0f + epsp[0];
                    const float* gp = aggr + (size_t)m * K + k0;
                    float4v g0 = *reinterpret_cast<const float4v*>(gp);
                    float4v g1 = *reinterpret_cast<const float4v*>(gp + 4);
                    #pragma unroll
                    for (int j = 0; j < 4; ++j) {
                        v0[j] = s1 * v0[j] + g0[j];
                        v1[j] = s1 * v1[j] + g1[j];
                    }
                }
                short8v f;
                #pragma unroll
                for (int j = 0; j < 4; ++j) {
                    f[j]     = (short)f2bf(v0[j]);
                    f[4 + j] = (short)f2bf(v1[j]);
                }
                afrag[s][kt] = f;
            }
        }
    }

    #pragma unroll 2
    for (int nt = 0; nt < NT; ++nt) {
        const int n = nt * 16 + row16;
        float4v acc[NSTRIP];
        #pragma unroll
        for (int s = 0; s < NSTRIP; ++s) acc[s] = (float4v){0.f, 0.f, 0.f, 0.f};

        #pragma unroll
        for (int kt = 0; kt < KT; ++kt) {
            short8v bfrag = *reinterpret_cast<const short8v*>(
                Wb + (size_t)n * K + kt * 32 + kgrp * 8);
            #pragma unroll
            for (int s = 0; s < NSTRIP; ++s)
                acc[s] = __builtin_amdgcn_mfma_f32_16x16x32_bf16(
                    afrag[s][kt], bfrag, acc[s], 0, 0, 0);
        }

        const float bv = (OMODE != 0) ? bias[n] : 0.f;
        #pragma unroll
        for (int s = 0; s < NSTRIP; ++s) {
            #pragma unroll
            for (int r = 0; r < 4; ++r) {
                const int m = (strip0 + s) * 16 + kgrp * 4 + r;
                float v = acc[s][r];
                if constexpr (OMODE == 1) v = fmaxf(v + bv, 0.f);
                if constexpr (OMODE == 2) v = v + bv;
                if constexpr (OMODE == 2)
                    ((float*)Out)[(size_t)m * NOUT + n] = v;
                else
                    ((unsigned short*)Out)[(size_t)m * NOUT + n] = f2bf(v);
            }
        }
    }
}

// ---------------------------------------------------------------------------
// Launch
// ---------------------------------------------------------------------------
extern "C" void kernel_launch(void* const* d_in, const int* in_sizes, int n_in,
                              void* d_out, int out_size, void* d_ws, size_t ws_size,
                              hipStream_t stream)
{
    const float* x     = (const float*)d_in[0];
    const int*   eidx  = (const int*)  d_in[1];
    const int*   etype = (const int*)  d_in[2];
    const float* W     = (const float*)d_in[3];
    const float* eps   = (const float*)d_in[4];
    const float* A_emb = (const float*)d_in[5];
    const float* B_emb = (const float*)d_in[6];
    const float* W1    = (const float*)d_in[7];
    const float* b1    = (const float*)d_in[8];
    const float* W2    = (const float*)d_in[9];
    const float* b2    = (const float*)d_in[10];
    const float* W3    = (const float*)d_in[11];
    const float* b3    = (const float*)d_in[12];

    char* wsb = (char*)d_ws;
    // ws layout (lifetime-overlapped):
    //   [0, 51.2MB)      : aggr (fp32 N x 128)      -- later reused as h2 (bf16 N x 256)
    //   [51.2, 102.4MB)  : y (bf16 N x 128)         -- later reused as h1 (bf16 N x 256)
    //   [102.4MB, +360KB): bf16 weights/embeddings
    float*          aggr = (float*)(wsb + 0);
    unsigned short* ybuf = (unsigned short*)(wsb + 51200000);
    unsigned short* h1   = (unsigned short*)(wsb + 51200000);
    unsigned short* h2   = (unsigned short*)(wsb + 0);
    unsigned short* wts  = (unsigned short*)(wsb + 102400000);

    unsigned short* Wb  = wts;
    unsigned short* W1b = wts + 16384;
    unsigned short* W2b = wts + 49152;
    unsigned short* W3b = wts + 114688;
    unsigned short* Ab  = wts + 147456;
    unsigned short* Bb  = wts + 163840;

    // 1) convert weights/embeddings to bf16
    wcvt_kernel<<<704, 256, 0, stream>>>(W, W1, W2, W3, A_emb, B_emb, wts);

    // 2) zero the aggregation buffer (ws is poisoned before every call)
    hipMemsetAsync(aggr, 0, (size_t)N_NODES * DIM * sizeof(float), stream);

    // 3) y = x @ W.T   (bf16 out)
    strip_gemm<128, 128, 0, 0><<<782, 256, 0, stream>>>(x, nullptr, nullptr, Wb, nullptr, ybuf);

    // 4) edge phase: aggr[dst] += y[src] + A_rt (B_rt . x[src])
    edge_kernel<<<N_EDGE / 4, 256, 0, stream>>>(x, eidx, etype, ybuf, Ab, Bb, aggr);

    // 5) h1 = relu(((1+eps)x + aggr) @ W1.T + b1)
    strip_gemm<128, 256, 1, 1><<<782, 256, 0, stream>>>(x, aggr, eps, W1b, b1, h1);

    // 6) h2 = relu(h1 @ W2.T + b2)
    strip_gemm<256, 256, 2, 1><<<782, 256, 0, stream>>>(h1, nullptr, nullptr, W2b, b2, h2);

    // 7) out = h2 @ W3.T + b3   (fp32)
    strip_gemm<256, 128, 2, 2><<<782, 256, 0, stream>>>(h2, nullptr, nullptr, W3b, b3, d_out);
}